// Round 17
// baseline (209.011 us; speedup 1.0000x reference)
//
#include <hip/hip_runtime.h>
#include <hip/hip_bf16.h>

// T=5 B=512 NA=16 S=64 A=16 HID=64 H=4 FD=256 LAT=128 N=8192 FIN=80
// Inputs fp32, output fp32. edge graph = complete per 16-agent batch (ignored
// input). seq = x[::16] (dst agent-0 only). attention query only at t=4.
//
// R17 vs R16 (199.8 us; k_gat 53.5, pre ~15, stage2 ~30, ~100 fixed):
//  1. k_gat: u1/ud1 LDS staging dropped -- P7 reads the 2KB u1g/ud1g straight
//     from global (L1-resident, broadcast addresses). LDS 37.4 -> 28.8 KB ->
//     5 blocks/CU (occupancy 33 -> ~42%) to close the latency-hiding gap.
//  2. k_pre: transpose remapped source-linear -- reads coalesced, writes
//     scattered (stores don't stall). Was read-strided (64 lines/wave-load).
//  k_stage2 = R12 verbatim. Algebra unchanged (R10).

__device__ __forceinline__ float wave_sum64(float v) {
    #pragma unroll
    for (int off = 32; off > 0; off >>= 1) v += __shfl_xor(v, off, 64);
    return v;
}
__device__ __forceinline__ float wave_max64(float v) {
    #pragma unroll
    for (int off = 32; off > 0; off >>= 1) v = fmaxf(v, __shfl_xor(v, off, 64));
    return v;
}

// ---------------- prologue: transposes (read-coalesced) + folds -------------
// blocks 0..1679: source-linear transposes; block 1680: u1/ud1/pa0/pd0 folds.
__global__ __launch_bounds__(256) void k_pre(
    const float* __restrict__ w0, const float* __restrict__ w1,
    const float* __restrict__ wip, const float* __restrict__ wop,
    const float* __restrict__ wm, const float* __restrict__ wlv,
    const float* __restrict__ wb,
    const float* __restrict__ as0, const float* __restrict__ ad0,
    const float* __restrict__ as1, const float* __restrict__ ad1,
    float* __restrict__ W0sT, float* __restrict__ W0aT,
    float* __restrict__ W1T,  float* __restrict__ wipT,
    float* __restrict__ wopT, float* __restrict__ whT,
    float* __restrict__ u1, float* __restrict__ ud1,
    float* __restrict__ pa0, float* __restrict__ pd0)
{
    const int tid = threadIdx.x;
    if (blockIdx.x < 1680) {
        int i = blockIdx.x * 256 + tid;          // 1680*256 = 430080 exact
        if (i < 20480) {                         // w0 (256x80), read linear
            int n = i / 80, k = i - n * 80;
            float v = w0[i];
            if (k < 64) W0sT[k * 256 + n] = v;
            else        W0aT[(k - 64) * 256 + n] = v;
        } else if (i < 86016) {                  // w1 (256x256)
            int j = i - 20480; int n = j >> 8, k = j & 255;
            W1T[k * 256 + n] = w1[j];
        } else if (i < 282624) {                 // wip (768x256)
            int j = i - 86016; int n = j >> 8, k = j & 255;
            wipT[k * 768 + n] = wip[j];
        } else if (i < 348160) {                 // wop (256x256)
            int j = i - 282624; int n = j >> 8, k = j & 255;
            wopT[k * 256 + n] = wop[j];
        } else if (i < 380928) {                 // wm (128x256)
            int j = i - 348160; int o = j >> 8, k = j & 255;
            whT[k * 320 + o] = wm[j];
        } else if (i < 413696) {                 // wlv (128x256)
            int j = i - 380928; int o = j >> 8, k = j & 255;
            whT[k * 320 + 128 + o] = wlv[j];
        } else {                                 // wb (64x256)
            int j = i - 413696; int o = j >> 8, k = j & 255;
            whT[k * 320 + 256 + o] = wb[j];
        }
        return;
    }
    // block 1680: u1[h][k] = sum_c as1[h][c]*w1[(h*64+c)][k]; ud1 with ad1
    for (int q = 0; q < 4; q++) {
        int idx = q * 256 + tid;                 // 1024
        int h = idx >> 8, k = idx & 255;
        float su = 0.f, sd = 0.f;
        for (int c = 0; c < 64; c++) {
            float wv = w1[(h * 64 + c) * 256 + k];
            su = fmaf(as1[h * 64 + c], wv, su);
            sd = fmaf(ad1[h * 64 + c], wv, sd);
        }
        u1[idx] = su; ud1[idx] = sd;
    }
    if (tid < 64) {
        int h = tid >> 4, k = tid & 15;
        float su = 0.f, sd = 0.f;
        for (int c = 0; c < 64; c++) {
            float wv = w0[(h * 64 + c) * 80 + 64 + k];
            su = fmaf(as0[h * 64 + c], wv, su);
            sd = fmaf(ad0[h * 64 + c], wv, sd);
        }
        pa0[tid] = su; pd0[tid] = sd;
    }
}

// ---------------- stage 1: 2-layer GAT, one block per (b,g) -----------------
// 2560 blocks, 256 threads; thread n = column; wave w = head (n>>6).
// 28.8 KB LDS -> 5 blocks/CU. u1/ud1 read from global in P7 (L1-resident).
__global__ __launch_bounds__(256) void k_gat(
    const float* __restrict__ sig,   // (T,B,64)
    const float* __restrict__ nact,  // (T,B,256)
    const float* __restrict__ W0sT,  // [64][256]
    const float* __restrict__ W0aT,  // [16][256]
    const float* __restrict__ W1T,   // [256][256]
    const float* __restrict__ u1g, const float* __restrict__ ud1g,   // [4][256]
    const float* __restrict__ pa0g, const float* __restrict__ pd0g,  // [4][16]
    const float* __restrict__ as0, const float* __restrict__ ad0,
    const float* __restrict__ b0, const float* __restrict__ b1,
    float* __restrict__ seqf)        // (2560,256)
{
    __shared__ __align__(16) char smem[28800];
    float* actL    = (float*)(smem + 0);       // [16][16]
    float* sigL    = (float*)(smem + 1024);    // [64]
    float* pa0L    = (float*)(smem + 1280);    // [64]
    float* pd0L    = (float*)(smem + 1536);    // [64]
    float* es0w    = (float*)(smem + 1792);    // [4][16]  (per-wave)
    float* ed0w    = (float*)(smem + 2048);    // [4][16]
    float* espL    = (float*)(smem + 2304);    // [16][4][4]
    float* es1L    = (float*)(smem + 3328);    // [16][4]
    float* edpL    = (float*)(smem + 3584);    // [4][4]
    float* alpha1L = (float*)(smem + 3648);    // [4][16]
    float* a0L     = (float*)(smem + 3904);    // [4][16][16]
    float* zL      = (float*)(smem + 8000);    // [4][260]
    float* x1L     = (float*)(smem + 12160);   // [16][260]

    const int tid = threadIdx.x;
    const int bg = blockIdx.x;
    const int b = bg / 5, g = bg - b * 5;
    const int n = tid, w = tid >> 6, lane = tid & 63;

    // P1: loads (u1/ud1 no longer staged)
    if (tid < 64) sigL[tid] = sig[(g * 512 + b) * 64 + tid];
    actL[tid] = nact[(g * 512 + b) * 256 + tid];
    if (tid >= 64 && tid < 128) {
        pa0L[tid - 64] = pa0g[tid - 64];
        pd0L[tid - 64] = pd0g[tid - 64];
    }
    __syncthreads();                                       // barrier 1

    // P2: S[n] in register; sS/dS wave-reduced into ALL lanes
    float S = 0.f;
    {
        const float4* sig4 = (const float4*)sigL;
        #pragma unroll 4
        for (int i = 0; i < 16; i++) {
            float4 sv = sig4[i];
            S = fmaf(sv.x, W0sT[(i * 4 + 0) * 256 + n], S);
            S = fmaf(sv.y, W0sT[(i * 4 + 1) * 256 + n], S);
            S = fmaf(sv.z, W0sT[(i * 4 + 2) * 256 + n], S);
            S = fmaf(sv.w, W0sT[(i * 4 + 3) * 256 + n], S);
        }
    }
    const float sS = wave_sum64(S * as0[n]);
    const float dS = wave_sum64(S * ad0[n]);

    // P3+P4 (wave-local, head w): es0/ed0 then alpha0 row
    if (lane < 16) {
        const int m = lane;
        float su = (m == 0) ? sS : 0.f;
        float sd = (m == 0) ? dS : 0.f;
        const float4* act4 = (const float4*)(actL + m * 16);
        const float4* pa4  = (const float4*)(pa0L + w * 16);
        const float4* pd4  = (const float4*)(pd0L + w * 16);
        #pragma unroll
        for (int q = 0; q < 4; q++) {
            float4 av = act4[q], pv = pa4[q], dv = pd4[q];
            su = fmaf(av.x, pv.x, su); su = fmaf(av.y, pv.y, su);
            su = fmaf(av.z, pv.z, su); su = fmaf(av.w, pv.w, su);
            sd = fmaf(av.x, dv.x, sd); sd = fmaf(av.y, dv.y, sd);
            sd = fmaf(av.z, dv.z, sd); sd = fmaf(av.w, dv.w, sd);
        }
        es0w[w * 16 + m] = su;
        ed0w[w * 16 + m] = sd;
    }
    if (lane < 16) {   // wave-synchronous with the write above
        const int j = lane;
        float ej = ed0w[w * 16 + j];
        float e[16], m = -1e30f;
        const float4* es4 = (const float4*)(es0w + w * 16);
        #pragma unroll
        for (int s4 = 0; s4 < 4; s4++) {
            float4 ev = es4[s4];
            float x;
            x = ev.x + ej; x = (x >= 0.f) ? x : 0.2f * x; e[s4*4+0] = x; m = fmaxf(m, x);
            x = ev.y + ej; x = (x >= 0.f) ? x : 0.2f * x; e[s4*4+1] = x; m = fmaxf(m, x);
            x = ev.z + ej; x = (x >= 0.f) ? x : 0.2f * x; e[s4*4+2] = x; m = fmaxf(m, x);
            x = ev.w + ej; x = (x >= 0.f) ? x : 0.2f * x; e[s4*4+3] = x; m = fmaxf(m, x);
        }
        float sum = 0.f;
        #pragma unroll
        for (int s = 0; s < 16; s++) { e[s] = __expf(e[s] - m); sum += e[s]; }
        float inv = 1.f / sum;
        float4* a04 = (float4*)(a0L + w * 256 + j * 16);
        #pragma unroll
        for (int s4 = 0; s4 < 4; s4++)
            a04[s4] = make_float4(e[s4 * 4] * inv, e[s4 * 4 + 1] * inv,
                                  e[s4 * 4 + 2] * inv, e[s4 * 4 + 3] * inv);
    }
    // a0L[w] produced & consumed by wave w only -> no block barrier

    // P56: xl0r in regs; x1r[j] via b128 a0L[w] broadcasts; store x1L
    float x1r[16];
    {
        float wr[16];
        #pragma unroll
        for (int k = 0; k < 16; k++) wr[k] = W0aT[k * 256 + n];
        const float4* act4 = (const float4*)actL;
        float xl0r[16];
        #pragma unroll
        for (int s = 0; s < 16; s++) {
            float a = 0.f;
            #pragma unroll
            for (int q = 0; q < 4; q++) {
                float4 av = act4[s * 4 + q];
                a = fmaf(av.x, wr[q * 4 + 0], a);
                a = fmaf(av.y, wr[q * 4 + 1], a);
                a = fmaf(av.z, wr[q * 4 + 2], a);
                a = fmaf(av.w, wr[q * 4 + 3], a);
            }
            xl0r[s] = a;
        }
        xl0r[0] += S;
        const float b0v = b0[n];
        const float4* a04 = (const float4*)(a0L + w * 256);
        #pragma unroll
        for (int j = 0; j < 16; j++) {
            float acc = b0v;
            #pragma unroll
            for (int s4 = 0; s4 < 4; s4++) {
                float4 a4 = a04[j * 4 + s4];
                acc = fmaf(a4.x, xl0r[s4 * 4 + 0], acc);
                acc = fmaf(a4.y, xl0r[s4 * 4 + 1], acc);
                acc = fmaf(a4.z, xl0r[s4 * 4 + 2], acc);
                acc = fmaf(a4.w, xl0r[s4 * 4 + 3], acc);
            }
            x1r[j] = fmaxf(acc, 0.f);
            x1L[j * 260 + n] = x1r[j];
        }
    }
    __syncthreads();                                       // barrier 2

    // P7: es1/ed1 partials; u1/ud1 straight from global (L1-hot broadcast)
    {
        const int m = tid & 15, h = (tid >> 4) & 3, p = tid >> 6;
        const float4* x4p = (const float4*)(x1L + m * 260 + p * 64);
        const float4* u4p = (const float4*)(u1g + h * 256 + p * 64);
        float a = 0.f;
        #pragma unroll
        for (int i = 0; i < 16; i++) {
            float4 xv = x4p[i], uv = u4p[i];
            a = fmaf(xv.x, uv.x, a);
            a = fmaf(xv.y, uv.y, a);
            a = fmaf(xv.z, uv.z, a);
            a = fmaf(xv.w, uv.w, a);
        }
        espL[m * 16 + h * 4 + p] = a;
        if (m == 0) {
            const float4* ud4p = (const float4*)(ud1g + h * 256 + p * 64);
            float ad = 0.f;
            #pragma unroll
            for (int i = 0; i < 16; i++) {
                float4 xv = x4p[i], uv = ud4p[i];
                ad = fmaf(xv.x, uv.x, ad);
                ad = fmaf(xv.y, uv.y, ad);
                ad = fmaf(xv.z, uv.z, ad);
                ad = fmaf(xv.w, uv.w, ad);
            }
            edpL[h * 4 + p] = ad;
        }
    }
    __syncthreads();                                       // barrier 3

    // P8 (wave 0, wave-synchronous): es1 sums then alpha1
    if (w == 0) {
        {
            const int m = lane >> 2, h = lane & 3;
            const float* e = espL + m * 16 + h * 4;
            es1L[m * 4 + h] = e[0] + e[1] + e[2] + e[3];
        }
        if (lane < 4) {
            const int h = lane;
            float ej = edpL[h * 4] + edpL[h * 4 + 1] + edpL[h * 4 + 2] + edpL[h * 4 + 3];
            float e[16], m = -1e30f;
            #pragma unroll
            for (int s = 0; s < 16; s++) {
                float x = es1L[s * 4 + h] + ej;
                x = (x >= 0.f) ? x : 0.2f * x;
                e[s] = x; m = fmaxf(m, x);
            }
            float sum = 0.f;
            #pragma unroll
            for (int s = 0; s < 16; s++) { e[s] = __expf(e[s] - m); sum += e[s]; }
            float inv = 1.f / sum;
            #pragma unroll
            for (int s = 0; s < 16; s++) alpha1L[h * 16 + s] = e[s] * inv;
        }
    }
    __syncthreads();                                       // barrier 4

    // P9: z[hh][n] = sum_s alpha1[hh][s] * x1r[s]  (registers)
    {
        const float4* a14 = (const float4*)alpha1L;
        #pragma unroll
        for (int hh = 0; hh < 4; hh++) {
            float zv = 0.f;
            #pragma unroll
            for (int s4 = 0; s4 < 4; s4++) {
                float4 a4 = a14[hh * 4 + s4];
                zv = fmaf(a4.x, x1r[s4 * 4 + 0], zv);
                zv = fmaf(a4.y, x1r[s4 * 4 + 1], zv);
                zv = fmaf(a4.z, x1r[s4 * 4 + 2], zv);
                zv = fmaf(a4.w, x1r[s4 * 4 + 3], zv);
            }
            zL[hh * 260 + n] = zv;
        }
    }
    __syncthreads();                                       // barrier 5

    // P10: seq[bg][n] = relu(z[w] . W1T[:,n] + b1[n])
    {
        const float4* zh = (const float4*)(zL + w * 260);
        float acc = b1[n];
        #pragma unroll 8
        for (int i = 0; i < 64; i++) {
            float4 z4 = zh[i];
            acc = fmaf(z4.x, W1T[(i * 4 + 0) * 256 + n], acc);
            acc = fmaf(z4.y, W1T[(i * 4 + 1) * 256 + n], acc);
            acc = fmaf(z4.z, W1T[(i * 4 + 2) * 256 + n], acc);
            acc = fmaf(z4.w, W1T[(i * 4 + 3) * 256 + n], acc);
        }
        seqf[bg * 256 + n] = fmaxf(acc, 0.f);
    }
}

// ---------------- stage 2: qkv + attention + out_proj + heads (R12) ---------
__global__ __launch_bounds__(768) void k_stage2(
    const float* __restrict__ seqf,  // (2560,256)
    const float* __restrict__ wipT,  // [256][768]
    const float* __restrict__ bip,
    const float* __restrict__ wopT,  // [256][256]
    const float* __restrict__ bop,
    const float* __restrict__ whT,   // [256][320]
    const float* __restrict__ bm, const float* __restrict__ blv,
    const float* __restrict__ bb,
    float* __restrict__ out)
{
    __shared__ float sseq[2][5][256];
    __shared__ float kL[2][5][256], vL[2][5][256], qL[2][256];
    __shared__ float ctxL[2][256], featL[2][256];
    __shared__ float beliefL[2][64];
    const int tid = threadIdx.x;
    const int b0 = blockIdx.x * 2;

    {   // flat copy (batch boundary at 1280)
        float* sflat = &sseq[0][0][0];
        for (int i = tid; i < 2560; i += 768)
            sflat[i] = seqf[b0 * 1280 + i];
    }
    __syncthreads();

    // qkv: kind 0 -> q (t=4, both gb); kind 1 -> k; kind 2 -> v
    {
        const int kind = tid >> 8, n = tid & 255;
        if (kind == 0) {
            float a0 = 0.f, a1 = 0.f;
            for (int k = 0; k < 256; k++) {
                float wv = wipT[k * 768 + n];
                a0 = fmaf(sseq[0][4][k], wv, a0);
                a1 = fmaf(sseq[1][4][k], wv, a1);
            }
            float bv = bip[n];
            qL[0][n] = a0 + bv; qL[1][n] = a1 + bv;
        } else {
            const float* wcol = wipT + kind * 256 + n;     // stride 768
            float acc[2][5];
            #pragma unroll
            for (int gb = 0; gb < 2; gb++)
                #pragma unroll
                for (int t = 0; t < 5; t++) acc[gb][t] = 0.f;
            for (int k = 0; k < 256; k++) {
                float wv = wcol[k * 768];
                #pragma unroll
                for (int gb = 0; gb < 2; gb++) {
                    #pragma unroll
                    for (int t = 0; t < 5; t++)
                        acc[gb][t] = fmaf(sseq[gb][t][k], wv, acc[gb][t]);
                }
            }
            float bv = bip[kind * 256 + n];
            float* dst = (kind == 1) ? &kL[0][0][0] : &vL[0][0][0];
            #pragma unroll
            for (int gb = 0; gb < 2; gb++)
                #pragma unroll
                for (int t = 0; t < 5; t++)
                    dst[gb * 1280 + t * 256 + n] = acc[gb][t] + bv;
        }
    }
    __syncthreads();

    // attention at q=4 (causal mask constant -> cancels)
    if (tid < 512) {
        const int gb = tid >> 8, col = tid & 255;
        float q4 = qL[gb][col];
        float sc[5];
        #pragma unroll
        for (int t = 0; t < 5; t++)
            sc[t] = wave_sum64(q4 * kL[gb][t][col]) * 0.125f;
        float m = sc[0];
        #pragma unroll
        for (int t = 1; t < 5; t++) m = fmaxf(m, sc[t]);
        float p[5], sum = 0.f;
        #pragma unroll
        for (int t = 0; t < 5; t++) { p[t] = __expf(sc[t] - m); sum += p[t]; }
        float inv = 1.f / sum, cv = 0.f;
        #pragma unroll
        for (int t = 0; t < 5; t++) cv = fmaf(p[t], vL[gb][t][col], cv);
        ctxL[gb][col] = cv * inv;
    }
    __syncthreads();

    // out_proj
    if (tid < 512) {
        const int gb = tid >> 8, n = tid & 255;
        float acc = 0.f;
        for (int k = 0; k < 256; k++)
            acc = fmaf(ctxL[gb][k], wopT[k * 256 + n], acc);
        featL[gb][n] = acc + bop[n];
    }
    __syncthreads();

    // heads: j in [0,320) for both gb
    if (tid < 640) {
        const int gb = tid / 320, j = tid - gb * 320;
        float acc = 0.f;
        for (int k = 0; k < 256; k++)
            acc = fmaf(featL[gb][k], whT[k * 320 + j], acc);
        if (j < 128) {
            out[(b0 + gb) * 128 + j] = acc + bm[j];
        } else if (j < 256) {
            out[65536 + (b0 + gb) * 128 + (j - 128)] = acc + blv[j - 128];
        } else {
            beliefL[gb][j - 256] = acc + bb[j - 256];
        }
    }
    __syncthreads();

    // belief softmax: wave 0 -> gb 0, wave 1 -> gb 1
    if (tid < 128) {
        int gb = tid >> 6, lane = tid & 63;
        float lg = beliefL[gb][lane];
        float m = wave_max64(lg);
        float e = __expf(lg - m);
        float s = wave_sum64(e);
        out[131072 + (b0 + gb) * 64 + lane] = e / s;
    }
}

// ---------------------------------------------------------------------------
extern "C" void kernel_launch(void* const* d_in, const int* in_sizes, int n_in,
                              void* d_out, int out_size, void* d_ws, size_t ws_size,
                              hipStream_t stream) {
    const float* sig  = (const float*)d_in[0];
    const float* nact = (const float*)d_in[1];
    const float* w0   = (const float*)d_in[2];
    const float* as0  = (const float*)d_in[3];
    const float* ad0  = (const float*)d_in[4];
    const float* b0   = (const float*)d_in[5];
    const float* w1   = (const float*)d_in[6];
    const float* as1  = (const float*)d_in[7];
    const float* ad1  = (const float*)d_in[8];
    const float* b1   = (const float*)d_in[9];
    const float* wip  = (const float*)d_in[10];
    const float* bip  = (const float*)d_in[11];
    const float* wop  = (const float*)d_in[12];
    const float* bop  = (const float*)d_in[13];
    const float* wm   = (const float*)d_in[14];
    const float* bm   = (const float*)d_in[15];
    const float* wlv  = (const float*)d_in[16];
    const float* blv  = (const float*)d_in[17];
    const float* wb   = (const float*)d_in[18];
    const float* bb   = (const float*)d_in[19];
    // d_in[20] = edge_index (deterministic complete graph) — unused.

    // ws layout (floats): seqf + transposes + folds. ~4.35 MB
    float* ws    = (float*)d_ws;
    float* seqf  = ws;                 // 655360
    float* tws   = ws + 655360;        // 430080:
    float* W0sT  = tws;                //   16384
    float* W0aT  = tws + 16384;        //   4096
    float* W1T   = tws + 20480;        //   65536
    float* wipT  = tws + 86016;        //   196608
    float* wopT  = tws + 282624;       //   65536
    float* whT   = tws + 348160;       //   81920
    float* u1    = ws + 1085440;       // 1024
    float* ud1   = ws + 1086464;       // 1024
    float* pa0   = ws + 1087488;       // 64
    float* pd0   = ws + 1087552;       // 64

    k_pre   <<<1681, 256, 0, stream>>>(w0, w1, wip, wop, wm, wlv, wb,
                                       as0, ad0, as1, ad1,
                                       W0sT, W0aT, W1T, wipT, wopT, whT,
                                       u1, ud1, pa0, pd0);
    k_gat   <<<2560, 256, 0, stream>>>(sig, nact, W0sT, W0aT, W1T,
                                       u1, ud1, pa0, pd0, as0, ad0, b0, b1, seqf);
    k_stage2<<<256, 768, 0, stream>>>(seqf, wipT, bip, wopT, bop, whT,
                                      bm, blv, bb, (float*)d_out);
}